// Round 1
// baseline (5988.394 us; speedup 1.0000x reference)
//
#include <hip/hip_runtime.h>
#include <hip/hip_bf16.h>

// ---------------------------------------------------------------------------
// FEDformer forward, fp32 baseline.
// B=32, N_NODES=200, T=512, D=512, H=8, HD=64, MODES=64, L=4, D_CONV=2048.
//
// rfft->keep64->mix->irfft is replaced by dense DFT matmuls:
//   Xft[b,hi,0:64]=sum_t q[b,t,hi]*cos(2pi m t/512)
//   Xft[b,hi,64:128]=sum_t q[b,t,hi]*(-sin(2pi m t/512))
//   Y = per-(h,m) 64x64 complex mix
//   attn[b,t,d]=sum_k G[k,t]*Y[b,d,k],  G re rows: 1/512 (m=0), 2cos/512;
//                                       G im rows: 0 (m=0), -2sin/512.
// ---------------------------------------------------------------------------

#define TILE 64
#define KT 16

// EPI: 0 = store, 1 = store+bias, 2 = store+bias+posenc(m=t,n=d),
//      3 = relu store, 4 = C += acc
template <int EPI>
__global__ __launch_bounds__(256) void gemm_k(
    const float* __restrict__ Ap, const float* __restrict__ Bp,
    float* __restrict__ Cp, int M, int N, int K,
    long long a_batch, long long lda_m, long long lda_k,
    long long b_batch, long long ldb_k, long long ldb_n,
    long long c_batch, const float* __restrict__ bias)
{
    __shared__ float As[KT][TILE + 4];
    __shared__ float Bs[KT][TILE + 4];
    const float* A = Ap + (long long)blockIdx.z * a_batch;
    const float* B = Bp + (long long)blockIdx.z * b_batch;
    float* C = Cp + (long long)blockIdx.z * c_batch;
    const int m0 = blockIdx.x * TILE;
    const int n0 = blockIdx.y * TILE;
    const int tid = threadIdx.x;
    const int tx = tid & 15, ty = tid >> 4;

    float acc[4][4] = {};

    for (int k0 = 0; k0 < K; k0 += KT) {
        // ---- load A tile into As[k][m] ----
        if (lda_k == 1) {
            #pragma unroll
            for (int i = 0; i < 4; ++i) {
                int idx = tid + i * 256;           // 64*16 = 1024
                int m = idx >> 4, k = idx & 15;    // k fastest (contiguous)
                float v = 0.f;
                if (k0 + k < K) v = A[(long long)(m0 + m) * lda_m + (long long)(k0 + k)];
                As[k][m] = v;
            }
        } else {
            #pragma unroll
            for (int i = 0; i < 4; ++i) {
                int idx = tid + i * 256;
                int k = idx >> 6, m = idx & 63;    // m fastest (contiguous)
                float v = 0.f;
                if (k0 + k < K) v = A[(long long)(m0 + m) * lda_m + (long long)(k0 + k) * lda_k];
                As[k][m] = v;
            }
        }
        // ---- load B tile into Bs[k][n] ----
        if (ldb_n == 1) {
            #pragma unroll
            for (int i = 0; i < 4; ++i) {
                int idx = tid + i * 256;
                int k = idx >> 6, n = idx & 63;    // n fastest
                float v = 0.f;
                if (k0 + k < K) v = B[(long long)(k0 + k) * ldb_k + (long long)(n0 + n)];
                Bs[k][n] = v;
            }
        } else {
            #pragma unroll
            for (int i = 0; i < 4; ++i) {
                int idx = tid + i * 256;
                int n = idx >> 4, k = idx & 15;    // k fastest
                float v = 0.f;
                if (k0 + k < K) v = B[(long long)(k0 + k) * ldb_k + (long long)(n0 + n) * ldb_n];
                Bs[k][n] = v;
            }
        }
        __syncthreads();
        #pragma unroll
        for (int kk = 0; kk < KT; ++kk) {
            float av[4], bv[4];
            #pragma unroll
            for (int i = 0; i < 4; ++i) av[i] = As[kk][ty * 4 + i];
            #pragma unroll
            for (int j = 0; j < 4; ++j) bv[j] = Bs[kk][tx * 4 + j];
            #pragma unroll
            for (int i = 0; i < 4; ++i)
                #pragma unroll
                for (int j = 0; j < 4; ++j)
                    acc[i][j] += av[i] * bv[j];
        }
        __syncthreads();
    }

    #pragma unroll
    for (int i = 0; i < 4; ++i) {
        int m = m0 + ty * 4 + i;
        #pragma unroll
        for (int j = 0; j < 4; ++j) {
            int n = n0 + tx * 4 + j;
            float v = acc[i][j];
            long long cidx = (long long)m * N + n;
            if (EPI == 1) {
                v += bias[n];
            } else if (EPI == 2) {
                v += bias[n];
                // positional embedding: even n -> sin(t * 10000^(-n/512)),
                // odd n -> cos(t * 10000^(-(n-1)/512))
                float e = -(float)(n & ~1) * (9.210340371976184f / 512.f);
                float ang = (float)m * __expf(e);
                v += (n & 1) ? cosf(ang) : sinf(ang);
            } else if (EPI == 3) {
                v = fmaxf(v, 0.f);
            } else if (EPI == 4) {
                v += C[cidx];
            }
            C[cidx] = v;
        }
    }
}

// Build DFT (F: 512x128 [t][m]) and inverse-DFT (G: 128x512 [k][t]) tables.
__global__ __launch_bounds__(256) void tables_k(float* __restrict__ F,
                                                float* __restrict__ G)
{
    int idx = blockIdx.x * 256 + threadIdx.x;   // 0..65535
    {
        int t = idx >> 7, mm = idx & 127;
        int m = mm & 63;
        float ang = (float)((m * t) & 511) * (6.283185307179586f / 512.f);
        F[idx] = (mm < 64) ? cosf(ang) : -sinf(ang);
    }
    {
        int k = idx >> 9, t = idx & 511;
        int m = k & 63;
        float ang = (float)((m * t) & 511) * (6.283185307179586f / 512.f);
        float v;
        if (k < 64) v = (m == 0) ? (1.f / 512.f) : (2.f / 512.f) * cosf(ang);
        else        v = (m == 0) ? 0.f : -(2.f / 512.f) * sinf(ang);
        G[idx] = v;
    }
}

// Per-(h,m) 64x64 complex mode mixing across all 32 batches.
// Xft/Y layout: [b][hi=512][128] with cols 0..63 = re, 64..127 = im.
__global__ __launch_bounds__(256) void modemix_k(
    const float* __restrict__ Xft, const float* __restrict__ fw_re,
    const float* __restrict__ fw_im, float* __restrict__ Y)
{
    const int h = blockIdx.x >> 6;
    const int m = blockIdx.x & 63;
    __shared__ float wre[64][64];   // [i][o]
    __shared__ float wim[64][64];
    __shared__ float xre[32][64];   // [b][i]
    __shared__ float xim[32][64];
    const int tid = threadIdx.x;

    const long long wbase = (long long)h * 262144 + m;  // (h,i=0,o=0,m)
    #pragma unroll
    for (int i = 0; i < 16; ++i) {
        int idx = tid + i * 256;                 // idx = i_*64 + o
        wre[idx >> 6][idx & 63] = fw_re[wbase + (long long)idx * 64];
        wim[idx >> 6][idx & 63] = fw_im[wbase + (long long)idx * 64];
    }
    #pragma unroll
    for (int i = 0; i < 8; ++i) {
        int idx = tid + i * 256;                 // idx = b*64 + i_
        int b = idx >> 6, ii = idx & 63;
        long long xbase = ((long long)b * 512 + h * 64 + ii) * 128 + m;
        xre[b][ii] = Xft[xbase];
        xim[b][ii] = Xft[xbase + 64];
    }
    __syncthreads();

    const int o = tid & 63;
    const int bq = tid >> 6;                     // 0..3, 8 b's each
    for (int bb = 0; bb < 8; ++bb) {
        int b = bq * 8 + bb;
        float yre = 0.f, yim = 0.f;
        #pragma unroll
        for (int i2 = 0; i2 < 64; ++i2) {
            float xr = xre[b][i2], xi = xim[b][i2];
            float wr = wre[i2][o], wi = wim[i2][o];
            yre += xr * wr - xi * wi;
            yim += xr * wi + xi * wr;
        }
        long long ybase = ((long long)b * 512 + h * 64 + o) * 128 + m;
        Y[ybase] = yre;
        Y[ybase + 64] = yim;
    }
}

// Mean-pool over t then 2-class head.
__global__ __launch_bounds__(256) void head_k(
    const float* __restrict__ act, const float* __restrict__ Wh,
    const float* __restrict__ bh, float* __restrict__ out)
{
    const int b = blockIdx.x;
    __shared__ float pooled[512];
    __shared__ float red[256];
    const float* A = act + (long long)b * 262144;
    for (int d = threadIdx.x; d < 512; d += 256) {
        float s = 0.f;
        for (int t = 0; t < 512; ++t) s += A[(long long)t * 512 + d];
        pooled[d] = s * (1.f / 512.f);
    }
    __syncthreads();
    for (int c = 0; c < 2; ++c) {
        float s = 0.f;
        for (int d = threadIdx.x; d < 512; d += 256)
            s += pooled[d] * Wh[c * 512 + d];
        red[threadIdx.x] = s;
        __syncthreads();
        for (int off = 128; off > 0; off >>= 1) {
            if (threadIdx.x < off) red[threadIdx.x] += red[threadIdx.x + off];
            __syncthreads();
        }
        if (threadIdx.x == 0) out[b * 2 + c] = red[0] + bh[c];
        __syncthreads();
    }
}

extern "C" void kernel_launch(void* const* d_in, const int* in_sizes, int n_in,
                              void* d_out, int out_size, void* d_ws, size_t ws_size,
                              hipStream_t stream)
{
    const float* x       = (const float*)d_in[0];   // (32,200,512)
    const float* W_embed = (const float*)d_in[1];   // (512,200)
    const float* b_embed = (const float*)d_in[2];   // (512,)
    const float* Wproj   = (const float*)d_in[3];   // (4,512,512)
    const float* bproj   = (const float*)d_in[4];   // (4,512)
    const float* fw_re   = (const float*)d_in[5];   // (4,8,64,64,64)
    const float* fw_im   = (const float*)d_in[6];
    const float* W1      = (const float*)d_in[7];   // (4,2048,512)
    const float* W2      = (const float*)d_in[8];   // (4,512,2048)
    const float* Wh      = (const float*)d_in[9];   // (2,512)
    const float* bh      = (const float*)d_in[10];  // (2,)
    float* out = (float*)d_out;

    float* ws   = (float*)d_ws;
    float* act  = ws;                 // 16384*512       = 8388608
    float* q    = act + 8388608;      // 8388608
    float* Xft  = q + 8388608;        // 32*512*128      = 2097152
    float* Y    = Xft + 2097152;      // 2097152
    float* Fb   = Y + 2097152;        // 512*128         = 65536
    float* Gb   = Fb + 65536;         // 128*512         = 65536
    float* ffn1 = Gb + 65536;         // up to 16384*2048 = 33554432

    long long base_f = (long long)(ffn1 - ws);
    long long avail = (long long)(ws_size / 4) - base_f;
    int chunk = 16384;
    if (avail < (long long)16384 * 2048) {
        long long c = (avail / 2048) & ~63LL;
        chunk = (c < 64) ? 64 : (c > 16384 ? 16384 : (int)c);
    }

    tables_k<<<256, 256, 0, stream>>>(Fb, Gb);

    // Embed: act[b,t,d] = sum_n x[b,n,t]*W_embed[d,n] + b_embed[d] + pe[t,d]
    gemm_k<2><<<dim3(8, 8, 32), 256, 0, stream>>>(
        x, W_embed, act, 512, 512, 200,
        102400LL, 1LL, 512LL,   0LL, 1LL, 200LL,   262144LL, b_embed);

    for (int l = 0; l < 4; ++l) {
        const float* Wp  = Wproj + (long long)l * 262144;
        const float* bp  = bproj + (long long)l * 512;
        const float* wre = fw_re + (long long)l * 2097152;
        const float* wim = fw_im + (long long)l * 2097152;
        const float* w1  = W1 + (long long)l * 1048576;
        const float* w2  = W2 + (long long)l * 1048576;

        // q = act @ Wp^T + bp   (16384 x 512 x 512)
        gemm_k<1><<<dim3(256, 8, 1), 256, 0, stream>>>(
            act, Wp, q, 16384, 512, 512,
            0LL, 512LL, 1LL,   0LL, 1LL, 512LL,   0LL, bp);

        // DFT: Xft[b,hi,:] = q_b^T @ F   (per b: 512 x 128 x 512)
        gemm_k<0><<<dim3(8, 2, 32), 256, 0, stream>>>(
            q, Fb, Xft, 512, 128, 512,
            262144LL, 1LL, 512LL,   0LL, 128LL, 1LL,   65536LL, nullptr);

        // complex mode mix
        modemix_k<<<512, 256, 0, stream>>>(Xft, wre, wim, Y);

        // iDFT + residual: act[b,t,d] += sum_k G[k,t]*Y[b,d,k]
        gemm_k<4><<<dim3(8, 8, 32), 256, 0, stream>>>(
            Gb, Y, act, 512, 512, 128,
            0LL, 1LL, 512LL,   65536LL, 1LL, 128LL,   262144LL, nullptr);

        // FFN (chunked over rows if ws is small)
        for (int r0 = 0; r0 < 16384; r0 += chunk) {
            int rows = 16384 - r0 < chunk ? 16384 - r0 : chunk;
            gemm_k<3><<<dim3(rows / 64, 32, 1), 256, 0, stream>>>(
                act + (long long)r0 * 512, w1, ffn1, rows, 2048, 512,
                0LL, 512LL, 1LL,   0LL, 1LL, 512LL,   0LL, nullptr);
            gemm_k<4><<<dim3(rows / 64, 8, 1), 256, 0, stream>>>(
                ffn1, w2, act + (long long)r0 * 512, rows, 512, 2048,
                0LL, 2048LL, 1LL,   0LL, 1LL, 2048LL,   0LL, nullptr);
        }
    }

    head_k<<<32, 256, 0, stream>>>(act, Wh, bh, out);
}

// Round 2
// 1159.501 us; speedup vs baseline: 5.1646x; 5.1646x over previous
//
#include <hip/hip_runtime.h>
#include <hip/hip_bf16.h>

// ---------------------------------------------------------------------------
// FEDformer forward. bf16 MFMA for all big GEMMs, fp32 residual stream.
// B=32, N_NODES=200, T=512, D=512, H=8, HD=64, MODES=64, L=4, D_CONV=2048.
//
// All MFMA GEMMs are NT: C[m][n] = sum_k A[m][k] * B[n][k], A/B bf16 row-major.
//   proj_T: q_T[b][hi][t] = sum_d Wp[hi][d]*act[b][t][d] + bp[hi]
//   DFT:    Xft[b][hi][mm] = sum_t q_T[b][hi][t]*FT[mm][t]
//   iDFT:   act[b][t][d] += sum_k GT[t][k]*Y[b][d][k]
//   FFN1:   ffn1 = relu(act @ W1^T); FFN2: act += ffn1 @ W2^T
// ---------------------------------------------------------------------------

typedef short s16x8 __attribute__((ext_vector_type(8)));
typedef float f32x4 __attribute__((ext_vector_type(4)));

#define GLOAD16(gp, lp)                                                        \
    __builtin_amdgcn_global_load_lds(                                          \
        (const __attribute__((address_space(1))) void*)(gp),                   \
        (__attribute__((address_space(3))) void*)(lp), 16, 0, 0)

// EPI: 0 = bf16 store, 1 = bf16 store + bias[row], 2 = relu bf16 store,
//      3 = fp32 C += acc
template <int EPI>
__global__ __launch_bounds__(256) void mgemm_k(
    const unsigned short* __restrict__ Ap, const unsigned short* __restrict__ Bp,
    void* __restrict__ Cp, int M, int N, int K,
    long long a_batch, long long b_batch, long long c_batch,
    const float* __restrict__ bias)
{
    __shared__ unsigned short As[128 * 32];
    __shared__ unsigned short Bs[128 * 32];
    const unsigned short* A = Ap + (long long)blockIdx.z * a_batch
                                 + (long long)blockIdx.x * 128 * K;
    const unsigned short* B = Bp + (long long)blockIdx.z * b_batch
                                 + (long long)blockIdx.y * 128 * K;
    const int tid  = threadIdx.x;
    const int wave = tid >> 6, lane = tid & 63;
    const int wr = wave >> 1, wc = wave & 1;

    f32x4 acc[4][4] = {};

    const int r  = lane >> 2;        // 0..15: row within 16-row segment
    const int kb = (lane & 3) * 8;   // 0,8,16,24: k element offset

    for (int k0 = 0; k0 < K; k0 += 32) {
        const unsigned short* Ag = A + k0;
        const unsigned short* Bg = B + k0;
        // stage 128x32 bf16 A-tile and B-tile; each wave: 2 A + 2 B loads.
        GLOAD16(Ag + (long long)(wave * 16 + r) * K + kb,      As + wave * 512);
        GLOAD16(Ag + (long long)(64 + wave * 16 + r) * K + kb, As + 2048 + wave * 512);
        GLOAD16(Bg + (long long)(wave * 16 + r) * K + kb,      Bs + wave * 512);
        GLOAD16(Bg + (long long)(64 + wave * 16 + r) * K + kb, Bs + 2048 + wave * 512);
        __syncthreads();

        const int frow = lane & 15;
        const int fk   = (lane >> 4) * 8;
        s16x8 af[4], bfr[4];
        #pragma unroll
        for (int i = 0; i < 4; ++i)
            af[i] = *(const s16x8*)&As[(wr * 64 + i * 16 + frow) * 32 + fk];
        #pragma unroll
        for (int j = 0; j < 4; ++j)
            bfr[j] = *(const s16x8*)&Bs[(wc * 64 + j * 16 + frow) * 32 + fk];
        #pragma unroll
        for (int i = 0; i < 4; ++i)
            #pragma unroll
            for (int j = 0; j < 4; ++j)
                acc[i][j] = __builtin_amdgcn_mfma_f32_16x16x32_bf16(
                    af[i], bfr[j], acc[i][j], 0, 0, 0);
        __syncthreads();
    }

    const long long Coff = (long long)blockIdx.z * c_batch;
    const int row0 = blockIdx.x * 128 + wr * 64;
    const int col0 = blockIdx.y * 128 + wc * 64;
    #pragma unroll
    for (int i = 0; i < 4; ++i) {
        #pragma unroll
        for (int j = 0; j < 4; ++j) {
            const int rbase = row0 + i * 16 + (lane >> 4) * 4;
            const int col   = col0 + j * 16 + (lane & 15);
            #pragma unroll
            for (int rr = 0; rr < 4; ++rr) {
                float v = acc[i][j][rr];
                const int row = rbase + rr;
                const long long cidx = Coff + (long long)row * N + col;
                if (EPI == 0) {
                    __hip_bfloat16 h = __float2bfloat16(v);
                    ((unsigned short*)Cp)[cidx] = *(unsigned short*)&h;
                } else if (EPI == 1) {
                    v += bias[row];
                    __hip_bfloat16 h = __float2bfloat16(v);
                    ((unsigned short*)Cp)[cidx] = *(unsigned short*)&h;
                } else if (EPI == 2) {
                    v = fmaxf(v, 0.f);
                    __hip_bfloat16 h = __float2bfloat16(v);
                    ((unsigned short*)Cp)[cidx] = *(unsigned short*)&h;
                } else {
                    ((float*)Cp)[cidx] += v;
                }
            }
        }
    }
}

// ---------------- fp32 tiled GEMM (embed only) -----------------------------
#define TILE 64
#define KT 16
// EPI2: store + bias + positional encoding
__global__ __launch_bounds__(256) void gemm_embed_k(
    const float* __restrict__ Ap, const float* __restrict__ Bp,
    float* __restrict__ Cp, int M, int N, int K,
    long long a_batch, long long lda_m, long long lda_k,
    long long ldb_k, long long ldb_n, long long c_batch,
    const float* __restrict__ bias)
{
    __shared__ float As[KT][TILE + 4];
    __shared__ float Bs[KT][TILE + 4];
    const float* A = Ap + (long long)blockIdx.z * a_batch;
    const float* B = Bp;
    float* C = Cp + (long long)blockIdx.z * c_batch;
    const int m0 = blockIdx.x * TILE;
    const int n0 = blockIdx.y * TILE;
    const int tid = threadIdx.x;
    const int tx = tid & 15, ty = tid >> 4;

    float acc[4][4] = {};
    for (int k0 = 0; k0 < K; k0 += KT) {
        #pragma unroll
        for (int i = 0; i < 4; ++i) {
            int idx = tid + i * 256;
            int k = idx >> 6, m = idx & 63;
            float v = 0.f;
            if (k0 + k < K) v = A[(long long)(m0 + m) * lda_m + (long long)(k0 + k) * lda_k];
            As[k][m] = v;
        }
        #pragma unroll
        for (int i = 0; i < 4; ++i) {
            int idx = tid + i * 256;
            int n = idx >> 4, k = idx & 15;
            float v = 0.f;
            if (k0 + k < K) v = B[(long long)(k0 + k) * ldb_k + (long long)(n0 + n) * ldb_n];
            Bs[k][n] = v;
        }
        __syncthreads();
        #pragma unroll
        for (int kk = 0; kk < KT; ++kk) {
            float av[4], bv[4];
            #pragma unroll
            for (int i = 0; i < 4; ++i) av[i] = As[kk][ty * 4 + i];
            #pragma unroll
            for (int j = 0; j < 4; ++j) bv[j] = Bs[kk][tx * 4 + j];
            #pragma unroll
            for (int i = 0; i < 4; ++i)
                #pragma unroll
                for (int j = 0; j < 4; ++j)
                    acc[i][j] += av[i] * bv[j];
        }
        __syncthreads();
    }
    #pragma unroll
    for (int i = 0; i < 4; ++i) {
        int m = m0 + ty * 4 + i;
        #pragma unroll
        for (int j = 0; j < 4; ++j) {
            int n = n0 + tx * 4 + j;
            float v = acc[i][j] + bias[n];
            float e = -(float)(n & ~1) * (9.210340371976184f / 512.f);
            float ang = (float)m * __expf(e);
            v += (n & 1) ? cosf(ang) : sinf(ang);
            C[(long long)m * N + n] = v;
        }
    }
}

// Build bf16 DFT tables. FT: [128][512] (mm,t); GT: [512][128] (t,k).
__global__ __launch_bounds__(256) void tables_k(unsigned short* __restrict__ FT,
                                                unsigned short* __restrict__ GT)
{
    int idx = blockIdx.x * 256 + threadIdx.x;   // 0..65535
    {
        int mm = idx >> 9, t = idx & 511;
        int m = mm & 63;
        float ang = (float)((m * t) & 511) * (6.283185307179586f / 512.f);
        float v = (mm < 64) ? cosf(ang) : -sinf(ang);
        __hip_bfloat16 h = __float2bfloat16(v);
        FT[idx] = *(unsigned short*)&h;
    }
    {
        int t = idx >> 7, k = idx & 127;
        int m = k & 63;
        float ang = (float)((m * t) & 511) * (6.283185307179586f / 512.f);
        float v;
        if (k < 64) v = (m == 0) ? (1.f / 512.f) : (2.f / 512.f) * cosf(ang);
        else        v = (m == 0) ? 0.f : -(2.f / 512.f) * sinf(ang);
        __hip_bfloat16 h = __float2bfloat16(v);
        GT[idx] = *(unsigned short*)&h;
    }
}

// fp32 -> bf16, vectorized (n4 = n/4 float4 groups)
__global__ __launch_bounds__(256) void f2b_k(const float* __restrict__ in,
                                             unsigned short* __restrict__ out, int n4)
{
    int i = blockIdx.x * 256 + threadIdx.x;
    int stride = gridDim.x * 256;
    for (; i < n4; i += stride) {
        float4 v = ((const float4*)in)[i];
        ushort4 o;
        __hip_bfloat16 h;
        h = __float2bfloat16(v.x); o.x = *(unsigned short*)&h;
        h = __float2bfloat16(v.y); o.y = *(unsigned short*)&h;
        h = __float2bfloat16(v.z); o.z = *(unsigned short*)&h;
        h = __float2bfloat16(v.w); o.w = *(unsigned short*)&h;
        ((ushort4*)out)[i] = o;
    }
}

// Per-(h,m) 64x64 complex mode mixing. Xft/Y: [b][hi][128] cols 0..63 re / 64..127 im.
__global__ __launch_bounds__(256) void modemix_k(
    const unsigned short* __restrict__ Xft, const float* __restrict__ fw_re,
    const float* __restrict__ fw_im, unsigned short* __restrict__ Y)
{
    const int h = blockIdx.x >> 6;
    const int m = blockIdx.x & 63;
    __shared__ float wre[64][64];   // [i][o]
    __shared__ float wim[64][64];
    __shared__ float xre[32][64];   // [b][i]
    __shared__ float xim[32][64];
    const int tid = threadIdx.x;

    const long long wbase = (long long)h * 262144 + m;
    #pragma unroll
    for (int i = 0; i < 16; ++i) {
        int idx = tid + i * 256;
        wre[idx >> 6][idx & 63] = fw_re[wbase + (long long)idx * 64];
        wim[idx >> 6][idx & 63] = fw_im[wbase + (long long)idx * 64];
    }
    #pragma unroll
    for (int i = 0; i < 8; ++i) {
        int idx = tid + i * 256;
        int b = idx >> 6, ii = idx & 63;
        long long xbase = ((long long)b * 512 + h * 64 + ii) * 128 + m;
        __hip_bfloat16_raw hr, hi2;
        hr.x = Xft[xbase];
        hi2.x = Xft[xbase + 64];
        xre[b][ii] = __bfloat162float(__hip_bfloat16(hr));
        xim[b][ii] = __bfloat162float(__hip_bfloat16(hi2));
    }
    __syncthreads();

    const int o = tid & 63;
    const int bq = tid >> 6;
    for (int bb = 0; bb < 8; ++bb) {
        int b = bq * 8 + bb;
        float yre = 0.f, yim = 0.f;
        #pragma unroll
        for (int i2 = 0; i2 < 64; ++i2) {
            float xr = xre[b][i2], xi = xim[b][i2];
            float wr = wre[i2][o], wi = wim[i2][o];
            yre += xr * wr - xi * wi;
            yim += xr * wi + xi * wr;
        }
        long long ybase = ((long long)b * 512 + h * 64 + o) * 128 + m;
        __hip_bfloat16 hr = __float2bfloat16(yre);
        __hip_bfloat16 hi2 = __float2bfloat16(yim);
        Y[ybase]      = *(unsigned short*)&hr;
        Y[ybase + 64] = *(unsigned short*)&hi2;
    }
}

// Mean-pool over t then 2-class head (fp32).
__global__ __launch_bounds__(256) void head_k(
    const float* __restrict__ act, const float* __restrict__ Wh,
    const float* __restrict__ bh, float* __restrict__ out)
{
    const int b = blockIdx.x;
    __shared__ float pooled[512];
    __shared__ float red[256];
    const float* A = act + (long long)b * 262144;
    for (int d = threadIdx.x; d < 512; d += 256) {
        float s = 0.f;
        for (int t = 0; t < 512; ++t) s += A[(long long)t * 512 + d];
        pooled[d] = s * (1.f / 512.f);
    }
    __syncthreads();
    for (int c = 0; c < 2; ++c) {
        float s = 0.f;
        for (int d = threadIdx.x; d < 512; d += 256)
            s += pooled[d] * Wh[c * 512 + d];
        red[threadIdx.x] = s;
        __syncthreads();
        for (int off = 128; off > 0; off >>= 1) {
            if (threadIdx.x < off) red[threadIdx.x] += red[threadIdx.x + off];
            __syncthreads();
        }
        if (threadIdx.x == 0) out[b * 2 + c] = red[0] + bh[c];
        __syncthreads();
    }
}

extern "C" void kernel_launch(void* const* d_in, const int* in_sizes, int n_in,
                              void* d_out, int out_size, void* d_ws, size_t ws_size,
                              hipStream_t stream)
{
    const float* x       = (const float*)d_in[0];   // (32,200,512)
    const float* W_embed = (const float*)d_in[1];   // (512,200)
    const float* b_embed = (const float*)d_in[2];   // (512,)
    const float* Wproj   = (const float*)d_in[3];   // (4,512,512)
    const float* bproj   = (const float*)d_in[4];   // (4,512)
    const float* fw_re   = (const float*)d_in[5];   // (4,8,64,64,64)
    const float* fw_im   = (const float*)d_in[6];
    const float* W1      = (const float*)d_in[7];   // (4,2048,512)
    const float* W2      = (const float*)d_in[8];   // (4,512,2048)
    const float* Wh      = (const float*)d_in[9];   // (2,512)
    const float* bh      = (const float*)d_in[10];  // (2,)
    float* out = (float*)d_out;

    float* act = (float*)d_ws;                       // 8388608 f
    unsigned short* actb = (unsigned short*)(act + 8388608); // 8388608 bf16
    unsigned short* qT   = actb + 8388608;           // 8388608
    unsigned short* Xft  = qT + 8388608;             // 2097152
    unsigned short* Yb   = Xft + 2097152;            // 2097152
    unsigned short* FT   = Yb + 2097152;             // 65536
    unsigned short* GT   = FT + 65536;               // 65536
    unsigned short* Wpb  = GT + 65536;               // 1048576
    unsigned short* W1b  = Wpb + 1048576;            // 4194304
    unsigned short* W2b  = W1b + 4194304;            // 4194304
    unsigned short* ffn1 = W2b + 4194304;            // 33554432 (full)

    // FFN chunking if workspace is short
    long long used_bytes = (char*)ffn1 - (char*)d_ws;
    long long avail_bf16 = ((long long)ws_size - used_bytes) / 2;
    int chunk = 16384;
    if (avail_bf16 < (long long)16384 * 2048) {
        long long c = (avail_bf16 / 2048) & ~127LL;
        chunk = (c < 128) ? 128 : (int)c;
    }

    tables_k<<<256, 256, 0, stream>>>(FT, GT);
    f2b_k<<<1024, 256, 0, stream>>>(Wproj, Wpb, 262144);
    f2b_k<<<2048, 256, 0, stream>>>(W1, W1b, 1048576);
    f2b_k<<<2048, 256, 0, stream>>>(W2, W2b, 1048576);

    // Embed (fp32): act[b,t,d] = sum_n x[b,n,t]*W_embed[d,n] + b_embed[d] + pe[t,d]
    gemm_embed_k<<<dim3(8, 8, 32), 256, 0, stream>>>(
        x, W_embed, act, 512, 512, 200,
        102400LL, 1LL, 512LL, 1LL, 200LL, 262144LL, b_embed);

    for (int l = 0; l < 4; ++l) {
        const unsigned short* Wp = Wpb + (long long)l * 262144;
        const float* bp  = bproj + (long long)l * 512;
        const float* wre = fw_re + (long long)l * 2097152;
        const float* wim = fw_im + (long long)l * 2097152;
        const unsigned short* w1 = W1b + (long long)l * 1048576;
        const unsigned short* w2 = W2b + (long long)l * 1048576;

        f2b_k<<<2048, 256, 0, stream>>>(act, actb, 2097152);

        // proj_T: q_T[b][hi][t] (bias by row=hi)
        mgemm_k<1><<<dim3(4, 4, 32), 256, 0, stream>>>(
            Wp, actb, qT, 512, 512, 512, 0LL, 262144LL, 262144LL, bp);

        // DFT: Xft[b][hi][mm]
        mgemm_k<0><<<dim3(4, 1, 32), 256, 0, stream>>>(
            qT, FT, Xft, 512, 128, 512, 262144LL, 0LL, 65536LL, nullptr);

        modemix_k<<<512, 256, 0, stream>>>(Xft, wre, wim, Yb);

        // iDFT + residual: act[b][t][d] += sum_k GT[t][k]*Y[b][d][k]
        mgemm_k<3><<<dim3(4, 4, 32), 256, 0, stream>>>(
            GT, Yb, act, 512, 512, 128, 0LL, 65536LL, 262144LL, nullptr);

        f2b_k<<<2048, 256, 0, stream>>>(act, actb, 2097152);

        // FFN
        for (int r0 = 0; r0 < 16384; r0 += chunk) {
            int rows = 16384 - r0 < chunk ? 16384 - r0 : chunk;
            mgemm_k<2><<<dim3(rows / 128, 16, 1), 256, 0, stream>>>(
                actb + (long long)r0 * 512, w1, ffn1, rows, 2048, 512,
                0LL, 0LL, 0LL, nullptr);
            mgemm_k<3><<<dim3(rows / 128, 4, 1), 256, 0, stream>>>(
                ffn1, w2, act + (long long)r0 * 512, rows, 512, 2048,
                0LL, 0LL, 0LL, nullptr);
        }
    }

    head_k<<<32, 256, 0, stream>>>(act, Wh, bh, out);
}